// Round 1
// baseline (1217.689 us; speedup 1.0000x reference)
//
#include <hip/hip_runtime.h>
#include <hip/hip_bf16.h>

#define N_NODES 16384
#define N_EDGES 262144
#define GD 300
#define N_GRAPHS 64

constexpr int BM = 64, BN = 64, BK = 16;

// ---------------- GEMM: C[M,N] = act(A[M,K] @ W[K,N] + bias[N]) ----------------
// M must be a multiple of BM (16384 is). N,K guarded.
template <bool RELU>
__global__ __launch_bounds__(256) void gemm_bias(
    const float* __restrict__ A, const float* __restrict__ W,
    const float* __restrict__ bias, float* __restrict__ C,
    int M, int N, int K) {
  __shared__ float As[BM][BK + 1];
  __shared__ float Bs[BK][BN + 1];

  const int bm = blockIdx.y * BM;
  const int bn = blockIdx.x * BN;
  const int t = threadIdx.x;
  const int tx = t & 15;   // 16 cols of threads
  const int ty = t >> 4;   // 16 rows of threads

  float acc[4][4] = {};

  for (int k0 = 0; k0 < K; k0 += BK) {
    // Load A tile 64x16 (1024 elems / 256 threads = 4 each)
#pragma unroll
    for (int i = 0; i < 4; ++i) {
      int idx = t + i * 256;
      int r = idx >> 4, c = idx & 15;
      int k = k0 + c;
      As[r][c] = (k < K) ? A[(size_t)(bm + r) * K + k] : 0.f;
    }
    // Load W tile 16x64
#pragma unroll
    for (int i = 0; i < 4; ++i) {
      int idx = t + i * 256;
      int r = idx >> 6, c = idx & 63;
      int k = k0 + r;
      int n = bn + c;
      Bs[r][c] = (k < K && n < N) ? W[(size_t)k * N + n] : 0.f;
    }
    __syncthreads();

#pragma unroll
    for (int kk = 0; kk < BK; ++kk) {
      float a[4], b[4];
#pragma unroll
      for (int i = 0; i < 4; ++i) a[i] = As[ty * 4 + i][kk];
#pragma unroll
      for (int j = 0; j < 4; ++j) b[j] = Bs[kk][tx * 4 + j];
#pragma unroll
      for (int i = 0; i < 4; ++i)
#pragma unroll
        for (int j = 0; j < 4; ++j) acc[i][j] = fmaf(a[i], b[j], acc[i][j]);
    }
    __syncthreads();
  }

#pragma unroll
  for (int i = 0; i < 4; ++i) {
    int r = bm + ty * 4 + i;
#pragma unroll
    for (int j = 0; j < 4; ++j) {
      int c = bn + tx * 4 + j;
      if (c < N) {
        float v = acc[i][j] + bias[c];
        if (RELU) v = fmaxf(v, 0.f);
        C[(size_t)r * N + c] = v;
      }
    }
  }
}

// ---------------- CSR build ----------------
__global__ void hist_kernel(const int* __restrict__ dst, int* __restrict__ cnt) {
  int e = blockIdx.x * blockDim.x + threadIdx.x;
  if (e < N_EDGES) atomicAdd(&cnt[dst[e]], 1);
}

// Single block of 256 threads; each thread owns 64 consecutive nodes.
__global__ __launch_bounds__(256) void scan_kernel(
    const int* __restrict__ cnt, int* __restrict__ row_ptr, int* __restrict__ row_fill) {
  __shared__ int sums[256];
  const int t = threadIdx.x;
  const int base = t * 64;
  int s = 0;
  for (int i = 0; i < 64; ++i) s += cnt[base + i];
  sums[t] = s;
  __syncthreads();
  // Hillis-Steele inclusive scan over 256 partials
  for (int off = 1; off < 256; off <<= 1) {
    int x = (t >= off) ? sums[t - off] : 0;
    __syncthreads();
    sums[t] += x;
    __syncthreads();
  }
  int run = sums[t] - s;  // exclusive prefix of this thread's chunk
  for (int i = 0; i < 64; ++i) {
    int c = cnt[base + i];
    row_ptr[base + i] = run;
    row_fill[base + i] = run;
    run += c;
  }
  if (t == 255) row_ptr[N_NODES] = run;
}

__global__ void scatter_kernel(const int* __restrict__ src, const int* __restrict__ dst,
                               int* __restrict__ row_fill, int* __restrict__ csr_src) {
  int e = blockIdx.x * blockDim.x + threadIdx.x;
  if (e >= N_EDGES) return;
  int pos = atomicAdd(&row_fill[dst[e]], 1);
  csr_src[pos] = src[e];
}

// ---------------- SpMM aggregate: agg[n,:] = sum_{j in row n} M[csr_src[j], :] --------
__global__ __launch_bounds__(320) void spmm_kernel(
    const float* __restrict__ Mfeat, const int* __restrict__ row_ptr,
    const int* __restrict__ csr_src, float* __restrict__ agg) {
  const int n = blockIdx.x;
  const int t = threadIdx.x;
  if (t >= GD) return;
  const int j0 = row_ptr[n], j1 = row_ptr[n + 1];
  float acc = 0.f;
  for (int j = j0; j < j1; ++j) {
    int s = csr_src[j];
    acc += Mfeat[(size_t)s * GD + t];
  }
  agg[(size_t)n * GD + t] = acc;
}

// ---------------- Readout: softmax(h @ Wro + bro) segment-summed by graph id ---------
__global__ __launch_bounds__(256) void readout_kernel(
    const float* __restrict__ h, const float* __restrict__ Wro,
    const float* __restrict__ bro, const int* __restrict__ gid,
    float* __restrict__ out) {
  const int node = blockIdx.x * 4 + (threadIdx.x >> 6);
  const int lane = threadIdx.x & 63;
  if (node >= N_NODES) return;
  const float* row = h + (size_t)node * GD;
  float d0 = 0.f, d1 = 0.f;
  for (int k = lane; k < GD; k += 64) {
    float v = row[k];
    d0 += v * Wro[k * 2 + 0];
    d1 += v * Wro[k * 2 + 1];
  }
#pragma unroll
  for (int off = 32; off; off >>= 1) {
    d0 += __shfl_down(d0, off);
    d1 += __shfl_down(d1, off);
  }
  if (lane == 0) {
    d0 += bro[0];
    d1 += bro[1];
    float m = fmaxf(d0, d1);
    float e0 = expf(d0 - m), e1 = expf(d1 - m);
    float inv = 1.f / (e0 + e1);
    int g = gid[node];
    atomicAdd(&out[g * 2 + 0], e0 * inv);
    atomicAdd(&out[g * 2 + 1], e1 * inv);
  }
}

// ---------------- host ----------------
extern "C" void kernel_launch(void* const* d_in, const int* in_sizes, int n_in,
                              void* d_out, int out_size, void* d_ws, size_t ws_size,
                              hipStream_t stream) {
  const float* node_feats = (const float*)d_in[0];
  const float* W_lift = (const float*)d_in[1];
  const float* b_lift = (const float*)d_in[2];
  const float* Wf[3] = {(const float*)d_in[3], (const float*)d_in[7], (const float*)d_in[11]};
  const float* bf[3] = {(const float*)d_in[4], (const float*)d_in[8], (const float*)d_in[12]};
  const float* Wo[3] = {(const float*)d_in[5], (const float*)d_in[9], (const float*)d_in[13]};
  const float* bo[3] = {(const float*)d_in[6], (const float*)d_in[10], (const float*)d_in[14]};
  const float* W_ro = (const float*)d_in[15];
  const float* b_ro = (const float*)d_in[16];
  const int* src = (const int*)d_in[17];
  const int* dst = (const int*)d_in[18];
  const int* gid = (const int*)d_in[19];
  float* out = (float*)d_out;

  const size_t NND = (size_t)N_NODES * GD;  // 4,915,200 floats
  float* bufA = (float*)d_ws;
  float* bufB = bufA + NND;
  int* cnt = (int*)(bufB + NND);
  int* row_ptr = cnt + N_NODES;
  int* row_fill = row_ptr + N_NODES + 16;  // 16385 used, padded
  int* csr_src = row_fill + N_NODES;

  // --- CSR build (per call; deterministic up to within-row order) ---
  hipMemsetAsync(cnt, 0, N_NODES * sizeof(int), stream);
  hist_kernel<<<N_EDGES / 256, 256, 0, stream>>>(dst, cnt);
  scan_kernel<<<1, 256, 0, stream>>>(cnt, row_ptr, row_fill);
  scatter_kernel<<<N_EDGES / 256, 256, 0, stream>>>(src, dst, row_fill, csr_src);

  dim3 ggrid((GD + BN - 1) / BN, N_NODES / BM);  // (5, 256)

  // --- lift: h(bufA) = node_feats @ W_lift + b_lift (no relu) ---
  gemm_bias<false><<<ggrid, 256, 0, stream>>>(node_feats, W_lift, b_lift, bufA,
                                              N_NODES, GD, GD);

  // --- 3 message-passing layers (gather commuted through the dense layer) ---
  float* A = bufA;
  float* B = bufB;
  for (int l = 0; l < 3; ++l) {
    // B = relu(A @ Wf + bf)   (node-level message features)
    gemm_bias<true><<<ggrid, 256, 0, stream>>>(A, Wf[l], bf[l], B, N_NODES, GD, GD);
    // A = segment_sum of gathered rows of B  (h is dead, safe to overwrite)
    spmm_kernel<<<N_NODES, 320, 0, stream>>>(B, row_ptr, csr_src, A);
    // B = relu(A @ Wo + bo)   (new h)
    gemm_bias<true><<<ggrid, 256, 0, stream>>>(A, Wo[l], bo[l], B, N_NODES, GD, GD);
    float* tmpp = A; A = B; B = tmpp;  // new h is in A now
  }

  // --- readout ---
  hipMemsetAsync(out, 0, (size_t)out_size * sizeof(float), stream);
  readout_kernel<<<N_NODES / 4, 256, 0, stream>>>(A, W_ro, b_ro, gid, out);
}

// Round 2
// 385.249 us; speedup vs baseline: 3.1608x; 3.1608x over previous
//
#include <hip/hip_runtime.h>
#include <hip/hip_bf16.h>

#define N_NODES 16384
#define N_EDGES 262144
#define GD 300        // real feature dim
#define DP 320        // padded feature dim (K and N padded; pads are exact zeros)
#define N_GRAPHS 64

typedef short bf16x8 __attribute__((ext_vector_type(8)));
typedef float f32x4 __attribute__((ext_vector_type(4)));

__device__ static inline unsigned short f2bf(float v) {
  __hip_bfloat16 b = __float2bfloat16(v);
  return __builtin_bit_cast(unsigned short, b);
}
__device__ static inline float bf2f(unsigned short u) {
  return __bfloat162float(__builtin_bit_cast(__hip_bfloat16, u));
}

#define GLOAD_LDS16(g, l)                                                    \
  __builtin_amdgcn_global_load_lds(                                          \
      (const __attribute__((address_space(1))) void*)(g),                    \
      (__attribute__((address_space(3))) void*)(l), 16, 0, 0)

// ================= bf16 MFMA GEMM =================
// C[M,DP] = act(A[M,DP](bf16) @ W[DP,DP] + bias), W given pre-transposed as
// Wt[n][k] (bf16, zero-padded). BM=64 rows/block, BN=160 cols/block, BK=64.
// 4 waves (2 row x 2 col), per-wave 32x80 output = 2x5 frags of 16x16.
// LDS rows are 128 B (64 bf16); 16B-slot s within a row stores global slot
// s ^ (row&7)  -> conflict-free ds_read_b128; staged via global_load_lds with
// pre-swizzled global source (linear LDS dest).
constexpr int BM = 64, BN = 160, BK = 64, NKT = DP / BK;  // 5 K-tiles
constexpr int A_BYTES = BM * 128;            // 8192
constexpr int B_BYTES = BN * 128;            // 20480
constexpr int BUF_BYTES = A_BYTES + B_BYTES; // 28672

template <bool RELU>
__global__ __launch_bounds__(256) void gemm_mfma(
    const unsigned short* __restrict__ A, const unsigned short* __restrict__ Wt,
    const float* __restrict__ biasP, unsigned short* __restrict__ C) {
  __shared__ __align__(16) char smem[2 * BUF_BYTES];  // 57344 B -> 2 blocks/CU

  const int bm = blockIdx.y * BM;
  const int bn = blockIdx.x * BN;
  const int t = threadIdx.x;
  const int w = t >> 6;   // wave 0..3
  const int l = t & 63;
  const int wr = w & 1;   // wave row (0/1) -> rows wr*32..+31
  const int wc = w >> 1;  // wave col (0/1) -> cols wc*80..+79

  // staging lane geometry: each gll instr covers 8 LDS rows (1024 B)
  const int lr = l >> 3;              // row within 8-row group
  const int sg = (l & 7) ^ lr;        // global 16B-slot for this lane

  f32x4 acc[2][5] = {};

  auto stage = [&](int tk, int buf) {
    const int k0 = tk * BK;  // element offset in K
    char* lb = smem + buf * BUF_BYTES;
#pragma unroll
    for (int i = 0; i < 7; ++i) {
      int g = w + 4 * i;  // 28 groups: 8 for A, 20 for Bt
      if (g < 8) {
        const unsigned short* gp =
            A + (size_t)(bm + g * 8 + lr) * DP + k0 + 8 * sg;
        GLOAD_LDS16(gp, lb + g * 1024);
      } else {
        int gb = g - 8;
        const unsigned short* gp =
            Wt + (size_t)(bn + gb * 8 + lr) * DP + k0 + 8 * sg;
        GLOAD_LDS16(gp, lb + A_BYTES + gb * 1024);
      }
    }
  };

  auto compute = [&](int buf) {
    const char* lA = smem + buf * BUF_BYTES;
    const char* lB = lA + A_BYTES;
#pragma unroll
    for (int ks = 0; ks < 2; ++ks) {  // two K=32 sub-steps
      bf16x8 a[2], b[5];
#pragma unroll
      for (int m = 0; m < 2; ++m) {
        int r = wr * 32 + m * 16 + (l & 15);
        int slot = (ks * 4 + (l >> 4)) ^ (r & 7);
        a[m] = *(const bf16x8*)(lA + r * 128 + slot * 16);
      }
#pragma unroll
      for (int n = 0; n < 5; ++n) {
        int r = wc * 80 + n * 16 + (l & 15);
        int slot = (ks * 4 + (l >> 4)) ^ (r & 7);
        b[n] = *(const bf16x8*)(lB + r * 128 + slot * 16);
      }
#pragma unroll
      for (int m = 0; m < 2; ++m)
#pragma unroll
        for (int n = 0; n < 5; ++n)
          acc[m][n] =
              __builtin_amdgcn_mfma_f32_16x16x32_bf16(a[m], b[n], acc[m][n], 0, 0, 0);
    }
  };

  stage(0, 0);
  for (int tk = 0; tk < NKT; ++tk) {
    asm volatile("s_waitcnt vmcnt(0)" ::: "memory");
    __syncthreads();
    if (tk + 1 < NKT) stage(tk + 1, (tk + 1) & 1);
    compute(tk & 1);
  }

  // epilogue: C/D layout col=lane&15, row=(lane>>4)*4+reg [guide m89]
#pragma unroll
  for (int m = 0; m < 2; ++m) {
#pragma unroll
    for (int n = 0; n < 5; ++n) {
      int col = bn + wc * 80 + n * 16 + (l & 15);
      float bv = biasP[col];
#pragma unroll
      for (int r = 0; r < 4; ++r) {
        int row = bm + wr * 32 + m * 16 + (l >> 4) * 4 + r;
        float v = acc[m][n][r] + bv;
        if (RELU) v = fmaxf(v, 0.f);
        C[(size_t)row * DP + col] = f2bf(v);
      }
    }
  }
}

// ================= CSR build =================
__global__ void hist_kernel(const int* __restrict__ dst, int* __restrict__ cnt) {
  int e = blockIdx.x * blockDim.x + threadIdx.x;
  if (e < N_EDGES) atomicAdd(&cnt[dst[e]], 1);
}

__global__ __launch_bounds__(256) void scan_kernel(
    const int* __restrict__ cnt, int* __restrict__ row_ptr, int* __restrict__ row_fill) {
  __shared__ int sums[256];
  const int t = threadIdx.x;
  const int base = t * 64;
  int s = 0;
  for (int i = 0; i < 64; ++i) s += cnt[base + i];
  sums[t] = s;
  __syncthreads();
  for (int off = 1; off < 256; off <<= 1) {
    int x = (t >= off) ? sums[t - off] : 0;
    __syncthreads();
    sums[t] += x;
    __syncthreads();
  }
  int run = sums[t] - s;
  for (int i = 0; i < 64; ++i) {
    int c = cnt[base + i];
    row_ptr[base + i] = run;
    row_fill[base + i] = run;
    run += c;
  }
  if (t == 255) row_ptr[N_NODES] = run;
}

__global__ void scatter_kernel(const int* __restrict__ src, const int* __restrict__ dst,
                               int* __restrict__ row_fill, int* __restrict__ csr_src) {
  int e = blockIdx.x * blockDim.x + threadIdx.x;
  if (e >= N_EDGES) return;
  int pos = atomicAdd(&row_fill[dst[e]], 1);
  csr_src[pos] = src[e];
}

// ================= SpMM aggregate (bf16 in/out, fp32 accum) =================
__global__ __launch_bounds__(320) void spmm_bf16(
    const unsigned short* __restrict__ Mfeat, const int* __restrict__ row_ptr,
    const int* __restrict__ csr_src, unsigned short* __restrict__ agg) {
  const int n = blockIdx.x;
  const int t = threadIdx.x;  // 0..319
  const int j0 = row_ptr[n], j1 = row_ptr[n + 1];
  float acc = 0.f;
  for (int j = j0; j < j1; ++j) {
    int s = csr_src[j];
    acc += bf2f(Mfeat[(size_t)s * DP + t]);
  }
  agg[(size_t)n * DP + t] = f2bf(acc);
}

// ================= readout: softmax + per-graph sum (LDS-binned) ============
__global__ __launch_bounds__(256) void readout_kernel(
    const unsigned short* __restrict__ h, const float* __restrict__ Wro,
    const float* __restrict__ bro, const int* __restrict__ gid,
    float* __restrict__ out) {
  __shared__ float wro[2 * DP];
  __shared__ float bins[2 * N_GRAPHS];
  const int t = threadIdx.x;
  if (t < 2 * N_GRAPHS) bins[t] = 0.f;
  for (int i = t; i < 2 * DP; i += 256) wro[i] = (i < 2 * GD) ? Wro[i] : 0.f;
  __syncthreads();

  const int w = t >> 6, l = t & 63;
  const float b0 = bro[0], b1 = bro[1];
  const int nodeBase = blockIdx.x * 64 + w * 16;
  for (int it = 0; it < 16; ++it) {
    int node = nodeBase + it;
    float d0 = 0.f, d1 = 0.f;
    if (l < 40) {  // 40 lanes x 8 bf16 = 320 cols
      bf16x8 v = *(const bf16x8*)(h + (size_t)node * DP + l * 8);
#pragma unroll
      for (int j = 0; j < 8; ++j) {
        float f = bf2f((unsigned short)v[j]);
        int k = l * 8 + j;
        d0 += f * wro[2 * k];
        d1 += f * wro[2 * k + 1];
      }
    }
#pragma unroll
    for (int off = 32; off; off >>= 1) {
      d0 += __shfl_down(d0, off);
      d1 += __shfl_down(d1, off);
    }
    if (l == 0) {
      d0 += b0; d1 += b1;
      float m = fmaxf(d0, d1);
      float e0 = expf(d0 - m), e1 = expf(d1 - m);
      float inv = 1.f / (e0 + e1);
      int g = gid[node];
      atomicAdd(&bins[2 * g], e0 * inv);
      atomicAdd(&bins[2 * g + 1], e1 * inv);
    }
  }
  __syncthreads();
  if (t < 2 * N_GRAPHS) {
    float v = bins[t];
    if (v != 0.f) atomicAdd(&out[t], v);
  }
}

// ================= conversions =================
__global__ void conv_feats(const float* __restrict__ nf, unsigned short* __restrict__ X) {
  int idx = blockIdx.x * 256 + threadIdx.x;  // < N_NODES*DP
  int r = idx / DP, c = idx - r * DP;
  X[idx] = f2bf(c < GD ? nf[(size_t)r * GD + c] : 0.f);
}

struct WPtrs {
  const float* W[7];
  const float* b[7];
};

__global__ void conv_weights(WPtrs p, unsigned short* __restrict__ Wt,
                             float* __restrict__ biasP) {
  int wi = blockIdx.y;
  int idx = blockIdx.x * 256 + threadIdx.x;  // < DP*DP
  int n = idx / DP, k = idx - n * DP;
  float v = (n < GD && k < GD) ? p.W[wi][(size_t)k * GD + n] : 0.f;
  Wt[(size_t)wi * DP * DP + idx] = f2bf(v);
  if (idx < DP) biasP[wi * DP + idx] = (idx < GD) ? p.b[wi][idx] : 0.f;
}

// ================= host =================
extern "C" void kernel_launch(void* const* d_in, const int* in_sizes, int n_in,
                              void* d_out, int out_size, void* d_ws, size_t ws_size,
                              hipStream_t stream) {
  const float* node_feats = (const float*)d_in[0];
  const int* src = (const int*)d_in[17];
  const int* dst = (const int*)d_in[18];
  const int* gid = (const int*)d_in[19];
  float* out = (float*)d_out;

  WPtrs wp;
  wp.W[0] = (const float*)d_in[1];   wp.b[0] = (const float*)d_in[2];   // lift
  wp.W[1] = (const float*)d_in[3];   wp.b[1] = (const float*)d_in[4];   // Wf1
  wp.W[2] = (const float*)d_in[5];   wp.b[2] = (const float*)d_in[6];   // Wo1
  wp.W[3] = (const float*)d_in[7];   wp.b[3] = (const float*)d_in[8];   // Wf2
  wp.W[4] = (const float*)d_in[9];   wp.b[4] = (const float*)d_in[10];  // Wo2
  wp.W[5] = (const float*)d_in[11];  wp.b[5] = (const float*)d_in[12];  // Wf3
  wp.W[6] = (const float*)d_in[13];  wp.b[6] = (const float*)d_in[14];  // Wo3
  const float* W_ro = (const float*)d_in[15];
  const float* b_ro = (const float*)d_in[16];

  char* p = (char*)d_ws;
  unsigned short* X = (unsigned short*)p;  p += (size_t)N_NODES * DP * 2;
  unsigned short* Y = (unsigned short*)p;  p += (size_t)N_NODES * DP * 2;
  unsigned short* Wt = (unsigned short*)p; p += (size_t)7 * DP * DP * 2;
  float* biasP = (float*)p;                p += 7 * DP * 4;
  int* cnt = (int*)p;                      p += N_NODES * 4;
  int* row_ptr = (int*)p;                  p += (N_NODES + 16) * 4;
  int* row_fill = (int*)p;                 p += N_NODES * 4;
  int* csr_src = (int*)p;                  p += N_EDGES * 4;

  // --- CSR build ---
  hipMemsetAsync(cnt, 0, N_NODES * sizeof(int), stream);
  hist_kernel<<<N_EDGES / 256, 256, 0, stream>>>(dst, cnt);
  scan_kernel<<<1, 256, 0, stream>>>(cnt, row_ptr, row_fill);
  scatter_kernel<<<N_EDGES / 256, 256, 0, stream>>>(src, dst, row_fill, csr_src);

  // --- conversions ---
  conv_feats<<<(N_NODES * DP) / 256, 256, 0, stream>>>(node_feats, X);
  conv_weights<<<dim3(DP * DP / 256, 7), 256, 0, stream>>>(wp, Wt, biasP);

  const size_t WSZ = (size_t)DP * DP;
  dim3 ggrid(DP / BN, N_NODES / BM);  // (2, 256) = 512 blocks

  // lift: Y = X @ W0 + b0 (no relu)
  gemm_mfma<false><<<ggrid, 256, 0, stream>>>(X, Wt + 0 * WSZ, biasP + 0 * DP, Y);

  // L1
  gemm_mfma<true><<<ggrid, 256, 0, stream>>>(Y, Wt + 1 * WSZ, biasP + 1 * DP, X);
  spmm_bf16<<<N_NODES, 320, 0, stream>>>(X, row_ptr, csr_src, Y);
  gemm_mfma<true><<<ggrid, 256, 0, stream>>>(Y, Wt + 2 * WSZ, biasP + 2 * DP, X);
  // L2
  gemm_mfma<true><<<ggrid, 256, 0, stream>>>(X, Wt + 3 * WSZ, biasP + 3 * DP, Y);
  spmm_bf16<<<N_NODES, 320, 0, stream>>>(Y, row_ptr, csr_src, X);
  gemm_mfma<true><<<ggrid, 256, 0, stream>>>(X, Wt + 4 * WSZ, biasP + 4 * DP, Y);
  // L3
  gemm_mfma<true><<<ggrid, 256, 0, stream>>>(Y, Wt + 5 * WSZ, biasP + 5 * DP, X);
  spmm_bf16<<<N_NODES, 320, 0, stream>>>(X, row_ptr, csr_src, Y);
  gemm_mfma<true><<<ggrid, 256, 0, stream>>>(Y, Wt + 6 * WSZ, biasP + 6 * DP, X);

  // --- readout ---
  hipMemsetAsync(out, 0, (size_t)out_size * sizeof(float), stream);
  readout_kernel<<<N_NODES / 64, 256, 0, stream>>>(X, W_ro, b_ro, gid, out);
}

// Round 3
// 279.823 us; speedup vs baseline: 4.3516x; 1.3768x over previous
//
#include <hip/hip_runtime.h>
#include <hip/hip_bf16.h>

#define N_NODES 16384
#define N_EDGES 262144
#define GD 300        // real feature dim
#define DP 320        // padded feature dim (K and N padded; pads are exact zeros)
#define N_GRAPHS 64

typedef short bf16x8 __attribute__((ext_vector_type(8)));
typedef float f32x4 __attribute__((ext_vector_type(4)));

__device__ static inline unsigned short f2bf(float v) {
  __hip_bfloat16 b = __float2bfloat16(v);
  return __builtin_bit_cast(unsigned short, b);
}
__device__ static inline float bf2f(unsigned short u) {
  return __bfloat162float(__builtin_bit_cast(__hip_bfloat16, u));
}

#define GLOAD_LDS16(g, l)                                                    \
  __builtin_amdgcn_global_load_lds(                                          \
      (const __attribute__((address_space(1))) void*)(g),                    \
      (__attribute__((address_space(3))) void*)(l), 16, 0, 0)

// ================= bf16 MFMA GEMM =================
// C[M,DP] = act(A[M,DP](bf16) @ W[DP,DP] + bias), Wt[n][k] pre-transposed.
// BM=64, BN=160, BK=64; 4 waves (2x2), per-wave 32x80 = 2x5 frags of 16x16.
// LDS rows 128 B; 16B-slot s stores global slot s^(row&7) -> conflict-free
// ds_read_b128; staged via global_load_lds with pre-swizzled global source.
constexpr int BM = 64, BN = 160, BK = 64, NKT = DP / BK;  // 5 K-tiles
constexpr int A_BYTES = BM * 128;            // 8192
constexpr int B_BYTES = BN * 128;            // 20480
constexpr int BUF_BYTES = A_BYTES + B_BYTES; // 28672

template <bool RELU>
__global__ __launch_bounds__(256) void gemm_mfma(
    const unsigned short* __restrict__ A, const unsigned short* __restrict__ Wt,
    const float* __restrict__ biasP, unsigned short* __restrict__ C) {
  __shared__ __align__(16) char smem[2 * BUF_BYTES];  // 57344 B -> 2 blocks/CU

  const int bm = blockIdx.y * BM;
  const int bn = blockIdx.x * BN;
  const int t = threadIdx.x;
  const int w = t >> 6;   // wave 0..3
  const int l = t & 63;
  const int wr = w & 1;   // wave row -> rows wr*32..+31
  const int wc = w >> 1;  // wave col -> cols wc*80..+79

  const int lr = l >> 3;              // row within 8-row group
  const int sg = (l & 7) ^ lr;        // pre-swizzled global 16B-slot

  f32x4 acc[2][5] = {};

  auto stage = [&](int tk, int buf) {
    const int k0 = tk * BK;
    char* lb = smem + buf * BUF_BYTES;
#pragma unroll
    for (int i = 0; i < 7; ++i) {
      int g = w + 4 * i;  // 28 groups: 8 for A, 20 for Bt
      if (g < 8) {
        const unsigned short* gp =
            A + (size_t)(bm + g * 8 + lr) * DP + k0 + 8 * sg;
        GLOAD_LDS16(gp, lb + g * 1024);
      } else {
        int gb = g - 8;
        const unsigned short* gp =
            Wt + (size_t)(bn + gb * 8 + lr) * DP + k0 + 8 * sg;
        GLOAD_LDS16(gp, lb + A_BYTES + gb * 1024);
      }
    }
  };

  auto compute = [&](int buf) {
    const char* lA = smem + buf * BUF_BYTES;
    const char* lB = lA + A_BYTES;
#pragma unroll
    for (int ks = 0; ks < 2; ++ks) {
      bf16x8 a[2], b[5];
#pragma unroll
      for (int m = 0; m < 2; ++m) {
        int r = wr * 32 + m * 16 + (l & 15);
        int slot = (ks * 4 + (l >> 4)) ^ (r & 7);
        a[m] = *(const bf16x8*)(lA + r * 128 + slot * 16);
      }
#pragma unroll
      for (int n = 0; n < 5; ++n) {
        int r = wc * 80 + n * 16 + (l & 15);
        int slot = (ks * 4 + (l >> 4)) ^ (r & 7);
        b[n] = *(const bf16x8*)(lB + r * 128 + slot * 16);
      }
#pragma unroll
      for (int m = 0; m < 2; ++m)
#pragma unroll
        for (int n = 0; n < 5; ++n)
          acc[m][n] =
              __builtin_amdgcn_mfma_f32_16x16x32_bf16(a[m], b[n], acc[m][n], 0, 0, 0);
    }
  };

  stage(0, 0);
  for (int tk = 0; tk < NKT; ++tk) {
    asm volatile("s_waitcnt vmcnt(0)" ::: "memory");
    __syncthreads();
    if (tk + 1 < NKT) stage(tk + 1, (tk + 1) & 1);
    compute(tk & 1);
  }

#pragma unroll
  for (int m = 0; m < 2; ++m) {
#pragma unroll
    for (int n = 0; n < 5; ++n) {
      int col = bn + wc * 80 + n * 16 + (l & 15);
      float bv = biasP[col];
#pragma unroll
      for (int r = 0; r < 4; ++r) {
        int row = bm + wr * 32 + m * 16 + (l >> 4) * 4 + r;
        float v = acc[m][n][r] + bv;
        if (RELU) v = fmaxf(v, 0.f);
        C[(size_t)row * DP + col] = f2bf(v);
      }
    }
  }
}

// ================= CSR build =================
__global__ void hist_kernel(const int* __restrict__ dst, int* __restrict__ cnt) {
  int e = blockIdx.x * blockDim.x + threadIdx.x;
  if (e < N_EDGES) atomicAdd(&cnt[dst[e]], 1);
}

__global__ __launch_bounds__(256) void scan_kernel(
    const int* __restrict__ cnt, int* __restrict__ row_ptr, int* __restrict__ row_fill) {
  __shared__ int sums[256];
  const int t = threadIdx.x;
  const int base = t * 64;
  int s = 0;
  for (int i = 0; i < 64; ++i) s += cnt[base + i];
  sums[t] = s;
  __syncthreads();
  for (int off = 1; off < 256; off <<= 1) {
    int x = (t >= off) ? sums[t - off] : 0;
    __syncthreads();
    sums[t] += x;
    __syncthreads();
  }
  int run = sums[t] - s;
  for (int i = 0; i < 64; ++i) {
    int c = cnt[base + i];
    row_ptr[base + i] = run;
    row_fill[base + i] = run;
    run += c;
  }
  if (t == 255) row_ptr[N_NODES] = run;
}

__global__ void scatter_kernel(const int* __restrict__ src, const int* __restrict__ dst,
                               int* __restrict__ row_fill, int* __restrict__ csr_src) {
  int e = blockIdx.x * blockDim.x + threadIdx.x;
  if (e >= N_EDGES) return;
  int pos = atomicAdd(&row_fill[dst[e]], 1);
  csr_src[pos] = src[e];
}

// ========== SpMM aggregate, column-phased for XCD-L2 residency ==========
// blockIdx.y = column tile (5 tiles x 64 cols). Blocks dispatch x-major, so
// the machine sweeps tile 0 everywhere, then tile 1, ... Each phase's gather
// working set = 16384 rows x 128 B = 2.0 MB -> fits each XCD's 4 MB L2.
// One wave per node; lane = column within tile; 4x unrolled gather.
__global__ __launch_bounds__(256) void spmm_phased(
    const unsigned short* __restrict__ Mfeat, const int* __restrict__ row_ptr,
    const int* __restrict__ csr_src, unsigned short* __restrict__ agg) {
  const int tile = blockIdx.y;
  const int node = blockIdx.x * 4 + (threadIdx.x >> 6);
  const int lane = threadIdx.x & 63;
  const int col = tile * 64 + lane;
  const int j0 = row_ptr[node], j1 = row_ptr[node + 1];
  const unsigned short* base = Mfeat + col;
  float acc = 0.f;
  int j = j0;
  for (; j + 4 <= j1; j += 4) {
    int s0 = csr_src[j], s1 = csr_src[j + 1];
    int s2 = csr_src[j + 2], s3 = csr_src[j + 3];
    unsigned short v0 = base[(size_t)s0 * DP];
    unsigned short v1 = base[(size_t)s1 * DP];
    unsigned short v2 = base[(size_t)s2 * DP];
    unsigned short v3 = base[(size_t)s3 * DP];
    acc += bf2f(v0) + bf2f(v1) + bf2f(v2) + bf2f(v3);
  }
  for (; j < j1; ++j) acc += bf2f(base[(size_t)csr_src[j] * DP]);
  agg[(size_t)node * DP + col] = f2bf(acc);
}

// ================= readout: softmax + per-graph sum (LDS-binned) ============
__global__ __launch_bounds__(256) void readout_kernel(
    const unsigned short* __restrict__ h, const float* __restrict__ Wro,
    const float* __restrict__ bro, const int* __restrict__ gid,
    float* __restrict__ out) {
  __shared__ float wro[2 * DP];
  __shared__ float bins[2 * N_GRAPHS];
  const int t = threadIdx.x;
  if (t < 2 * N_GRAPHS) bins[t] = 0.f;
  for (int i = t; i < 2 * DP; i += 256) wro[i] = (i < 2 * GD) ? Wro[i] : 0.f;
  __syncthreads();

  const int w = t >> 6, l = t & 63;
  const float b0 = bro[0], b1 = bro[1];
  const int nodeBase = blockIdx.x * 64 + w * 16;
  for (int it = 0; it < 16; ++it) {
    int node = nodeBase + it;
    float d0 = 0.f, d1 = 0.f;
    if (l < 40) {
      bf16x8 v = *(const bf16x8*)(h + (size_t)node * DP + l * 8);
#pragma unroll
      for (int j = 0; j < 8; ++j) {
        float f = bf2f((unsigned short)v[j]);
        int k = l * 8 + j;
        d0 += f * wro[2 * k];
        d1 += f * wro[2 * k + 1];
      }
    }
#pragma unroll
    for (int off = 32; off; off >>= 1) {
      d0 += __shfl_down(d0, off);
      d1 += __shfl_down(d1, off);
    }
    if (l == 0) {
      d0 += b0; d1 += b1;
      float m = fmaxf(d0, d1);
      float e0 = expf(d0 - m), e1 = expf(d1 - m);
      float inv = 1.f / (e0 + e1);
      int g = gid[node];
      atomicAdd(&bins[2 * g], e0 * inv);
      atomicAdd(&bins[2 * g + 1], e1 * inv);
    }
  }
  __syncthreads();
  if (t < 2 * N_GRAPHS) {
    float v = bins[t];
    if (v != 0.f) atomicAdd(&out[t], v);
  }
}

// ================= conversions =================
__global__ void conv_feats(const float* __restrict__ nf, unsigned short* __restrict__ X) {
  int idx = blockIdx.x * 256 + threadIdx.x;  // over N_NODES * 40 groups of 8
  int r = idx / 40, j = idx - r * 40;
  int c0 = j * 8;
  const float* rp = nf + (size_t)r * GD + c0;
  bf16x8 o;
  if (c0 + 8 <= GD) {
    float4 a = *(const float4*)rp;
    float4 b = *(const float4*)(rp + 4);
    o[0] = f2bf(a.x); o[1] = f2bf(a.y); o[2] = f2bf(a.z); o[3] = f2bf(a.w);
    o[4] = f2bf(b.x); o[5] = f2bf(b.y); o[6] = f2bf(b.z); o[7] = f2bf(b.w);
  } else {
#pragma unroll
    for (int i = 0; i < 8; ++i) {
      int c = c0 + i;
      o[i] = f2bf(c < GD ? rp[i] : 0.f);
    }
  }
  *(bf16x8*)(X + (size_t)idx * 8) = o;
}

struct WPtrs {
  const float* W[7];
  const float* b[7];
};

__global__ void conv_weights(WPtrs p, unsigned short* __restrict__ Wt,
                             float* __restrict__ biasP) {
  int wi = blockIdx.y;
  int idx = blockIdx.x * 256 + threadIdx.x;  // < DP*DP
  int n = idx / DP, k = idx - n * DP;
  float v = (n < GD && k < GD) ? p.W[wi][(size_t)k * GD + n] : 0.f;
  Wt[(size_t)wi * DP * DP + idx] = f2bf(v);
  if (idx < DP) biasP[wi * DP + idx] = (idx < GD) ? p.b[wi][idx] : 0.f;
}

// ================= host =================
extern "C" void kernel_launch(void* const* d_in, const int* in_sizes, int n_in,
                              void* d_out, int out_size, void* d_ws, size_t ws_size,
                              hipStream_t stream) {
  const float* node_feats = (const float*)d_in[0];
  const int* src = (const int*)d_in[17];
  const int* dst = (const int*)d_in[18];
  const int* gid = (const int*)d_in[19];
  float* out = (float*)d_out;

  WPtrs wp;
  wp.W[0] = (const float*)d_in[1];   wp.b[0] = (const float*)d_in[2];   // lift
  wp.W[1] = (const float*)d_in[3];   wp.b[1] = (const float*)d_in[4];   // Wf1
  wp.W[2] = (const float*)d_in[5];   wp.b[2] = (const float*)d_in[6];   // Wo1
  wp.W[3] = (const float*)d_in[7];   wp.b[3] = (const float*)d_in[8];   // Wf2
  wp.W[4] = (const float*)d_in[9];   wp.b[4] = (const float*)d_in[10];  // Wo2
  wp.W[5] = (const float*)d_in[11];  wp.b[5] = (const float*)d_in[12];  // Wf3
  wp.W[6] = (const float*)d_in[13];  wp.b[6] = (const float*)d_in[14];  // Wo3
  const float* W_ro = (const float*)d_in[15];
  const float* b_ro = (const float*)d_in[16];

  char* p = (char*)d_ws;
  unsigned short* X = (unsigned short*)p;  p += (size_t)N_NODES * DP * 2;
  unsigned short* Y = (unsigned short*)p;  p += (size_t)N_NODES * DP * 2;
  unsigned short* Wt = (unsigned short*)p; p += (size_t)7 * DP * DP * 2;
  float* biasP = (float*)p;                p += 7 * DP * 4;
  int* cnt = (int*)p;                      p += N_NODES * 4;
  int* row_ptr = (int*)p;                  p += (N_NODES + 16) * 4;
  int* row_fill = (int*)p;                 p += N_NODES * 4;
  int* csr_src = (int*)p;                  p += N_EDGES * 4;

  // --- CSR build ---
  hipMemsetAsync(cnt, 0, N_NODES * sizeof(int), stream);
  hist_kernel<<<N_EDGES / 256, 256, 0, stream>>>(dst, cnt);
  scan_kernel<<<1, 256, 0, stream>>>(cnt, row_ptr, row_fill);
  scatter_kernel<<<N_EDGES / 256, 256, 0, stream>>>(src, dst, row_fill, csr_src);

  // --- conversions ---
  conv_feats<<<(N_NODES * 40) / 256, 256, 0, stream>>>(node_feats, X);
  conv_weights<<<dim3(DP * DP / 256, 7), 256, 0, stream>>>(wp, Wt, biasP);

  const size_t WSZ = (size_t)DP * DP;
  dim3 ggrid(DP / BN, N_NODES / BM);       // (2, 256) = 512 blocks
  dim3 sgrid(N_NODES / 4, 5);              // (4096 node-blocks, 5 col phases)

  // lift: Y = X @ W0 + b0 (no relu)
  gemm_mfma<false><<<ggrid, 256, 0, stream>>>(X, Wt + 0 * WSZ, biasP + 0 * DP, Y);

  // L1
  gemm_mfma<true><<<ggrid, 256, 0, stream>>>(Y, Wt + 1 * WSZ, biasP + 1 * DP, X);
  spmm_phased<<<sgrid, 256, 0, stream>>>(X, row_ptr, csr_src, Y);
  gemm_mfma<true><<<ggrid, 256, 0, stream>>>(Y, Wt + 2 * WSZ, biasP + 2 * DP, X);
  // L2
  gemm_mfma<true><<<ggrid, 256, 0, stream>>>(X, Wt + 3 * WSZ, biasP + 3 * DP, Y);
  spmm_phased<<<sgrid, 256, 0, stream>>>(Y, row_ptr, csr_src, X);
  gemm_mfma<true><<<ggrid, 256, 0, stream>>>(X, Wt + 4 * WSZ, biasP + 4 * DP, Y);
  // L3
  gemm_mfma<true><<<ggrid, 256, 0, stream>>>(Y, Wt + 5 * WSZ, biasP + 5 * DP, X);
  spmm_phased<<<sgrid, 256, 0, stream>>>(X, row_ptr, csr_src, Y);
  gemm_mfma<true><<<ggrid, 256, 0, stream>>>(Y, Wt + 6 * WSZ, biasP + 6 * DP, X);

  // --- readout ---
  hipMemsetAsync(out, 0, (size_t)out_size * sizeof(float), stream);
  readout_kernel<<<N_NODES / 64, 256, 0, stream>>>(X, W_ro, b_ro, gid, out);
}

// Round 4
// 211.464 us; speedup vs baseline: 5.7584x; 1.3233x over previous
//
#include <hip/hip_runtime.h>
#include <hip/hip_bf16.h>

#define N_NODES 16384
#define N_EDGES 262144
#define GD 300        // real feature dim
#define DP 320        // padded feature dim (pads are exact zeros)
#define N_GRAPHS 64
#define NTILE 5       // 5 column tiles of 64

typedef short bf16x8 __attribute__((ext_vector_type(8)));
typedef float f32x4 __attribute__((ext_vector_type(4)));

__device__ static inline unsigned short f2bf(float v) {
  __hip_bfloat16 b = __float2bfloat16(v);
  return __builtin_bit_cast(unsigned short, b);
}
__device__ static inline float bf2f(unsigned short u) {
  return __bfloat162float(__builtin_bit_cast(__hip_bfloat16, u));
}

#define GLOAD_LDS16(g, l)                                                    \
  __builtin_amdgcn_global_load_lds(                                          \
      (const __attribute__((address_space(1))) void*)(g),                    \
      (__attribute__((address_space(3))) void*)(l), 16, 0, 0)

// ================= bf16 MFMA GEMM =================
// C[M,DP] = act(A[M,DP](bf16) @ W + bias), Wt[n][k] pre-transposed bf16.
// BM=64, BN=160, BK=64; 4 waves (2x2), per-wave 32x80 = 2x5 frags of 16x16.
// LDS rows 128 B; 16B-slot s stores global slot s^(row&7) -> conflict-free
// ds_read_b128; staged via global_load_lds with pre-swizzled global source.
// TILED: store C in column-tile-major Mt[tile][row][64] for the SpMM gather.
constexpr int BM = 64, BN = 160, BK = 64, NKT = DP / BK;  // 5 K-tiles
constexpr int A_BYTES = BM * 128;            // 8192
constexpr int B_BYTES = BN * 128;            // 20480
constexpr int BUF_BYTES = A_BYTES + B_BYTES; // 28672

template <bool RELU, bool TILED>
__global__ __launch_bounds__(256) void gemm_mfma(
    const unsigned short* __restrict__ A, const unsigned short* __restrict__ Wt,
    const float* __restrict__ biasP, unsigned short* __restrict__ C) {
  __shared__ __align__(16) char smem[2 * BUF_BYTES];  // 57344 B -> 2 blocks/CU

  const int bm = blockIdx.y * BM;
  const int bn = blockIdx.x * BN;
  const int t = threadIdx.x;
  const int w = t >> 6;   // wave 0..3
  const int l = t & 63;
  const int wr = w & 1;   // wave row -> rows wr*32..+31
  const int wc = w >> 1;  // wave col -> cols wc*80..+79

  const int lr = l >> 3;              // row within 8-row group
  const int sg = (l & 7) ^ lr;        // pre-swizzled global 16B-slot

  f32x4 acc[2][5] = {};

  auto stage = [&](int tk, int buf) {
    const int k0 = tk * BK;
    char* lb = smem + buf * BUF_BYTES;
#pragma unroll
    for (int i = 0; i < 7; ++i) {
      int g = w + 4 * i;  // 28 groups: 8 for A, 20 for Bt
      if (g < 8) {
        const unsigned short* gp =
            A + (size_t)(bm + g * 8 + lr) * DP + k0 + 8 * sg;
        GLOAD_LDS16(gp, lb + g * 1024);
      } else {
        int gb = g - 8;
        const unsigned short* gp =
            Wt + (size_t)(bn + gb * 8 + lr) * DP + k0 + 8 * sg;
        GLOAD_LDS16(gp, lb + A_BYTES + gb * 1024);
      }
    }
  };

  auto compute = [&](int buf) {
    const char* lA = smem + buf * BUF_BYTES;
    const char* lB = lA + A_BYTES;
#pragma unroll
    for (int ks = 0; ks < 2; ++ks) {
      bf16x8 a[2], b[5];
#pragma unroll
      for (int m = 0; m < 2; ++m) {
        int r = wr * 32 + m * 16 + (l & 15);
        int slot = (ks * 4 + (l >> 4)) ^ (r & 7);
        a[m] = *(const bf16x8*)(lA + r * 128 + slot * 16);
      }
#pragma unroll
      for (int n = 0; n < 5; ++n) {
        int r = wc * 80 + n * 16 + (l & 15);
        int slot = (ks * 4 + (l >> 4)) ^ (r & 7);
        b[n] = *(const bf16x8*)(lB + r * 128 + slot * 16);
      }
#pragma unroll
      for (int m = 0; m < 2; ++m)
#pragma unroll
        for (int n = 0; n < 5; ++n)
          acc[m][n] =
              __builtin_amdgcn_mfma_f32_16x16x32_bf16(a[m], b[n], acc[m][n], 0, 0, 0);
    }
  };

  stage(0, 0);
  for (int tk = 0; tk < NKT; ++tk) {
    asm volatile("s_waitcnt vmcnt(0)" ::: "memory");
    __syncthreads();
    if (tk + 1 < NKT) stage(tk + 1, (tk + 1) & 1);
    compute(tk & 1);
  }

#pragma unroll
  for (int m = 0; m < 2; ++m) {
#pragma unroll
    for (int n = 0; n < 5; ++n) {
      int col = bn + wc * 80 + n * 16 + (l & 15);
      float bv = biasP[col];
#pragma unroll
      for (int r = 0; r < 4; ++r) {
        int row = bm + wr * 32 + m * 16 + (l >> 4) * 4 + r;
        float v = acc[m][n][r] + bv;
        if (RELU) v = fmaxf(v, 0.f);
        size_t idx;
        if (TILED)  // each 16-wide frag lies in one 64-col tile (16 | 64)
          idx = ((size_t)(col >> 6) * N_NODES + row) * 64 + (col & 63);
        else
          idx = (size_t)row * DP + col;
        C[idx] = f2bf(v);
      }
    }
  }
}

// ================= CSR build =================
__global__ void hist_kernel(const int* __restrict__ dst, int* __restrict__ cnt) {
  int e = blockIdx.x * blockDim.x + threadIdx.x;
  if (e < N_EDGES) atomicAdd(&cnt[dst[e]], 1);
}

__global__ __launch_bounds__(256) void scan_kernel(
    const int* __restrict__ cnt, int* __restrict__ row_ptr, int* __restrict__ row_fill) {
  __shared__ int sums[256];
  const int t = threadIdx.x;
  const int base = t * 64;
  int s = 0;
  for (int i = 0; i < 64; ++i) s += cnt[base + i];
  sums[t] = s;
  __syncthreads();
  for (int off = 1; off < 256; off <<= 1) {
    int x = (t >= off) ? sums[t - off] : 0;
    __syncthreads();
    sums[t] += x;
    __syncthreads();
  }
  int run = sums[t] - s;
  for (int i = 0; i < 64; ++i) {
    int c = cnt[base + i];
    row_ptr[base + i] = run;
    row_fill[base + i] = run;
    run += c;
  }
  if (t == 255) row_ptr[N_NODES] = run;
}

__global__ void scatter_kernel(const int* __restrict__ src, const int* __restrict__ dst,
                               int* __restrict__ row_fill, int* __restrict__ csr_src) {
  int e = blockIdx.x * blockDim.x + threadIdx.x;
  if (e >= N_EDGES) return;
  int pos = atomicAdd(&row_fill[dst[e]], 1);
  csr_src[pos] = src[e];
}

// ========== SpMM aggregate: tiled gather, L2-resident per column phase ======
// Mt layout [NTILE][N_NODES][64] bf16: per phase the gathered slice is 2 MB
// (fits each XCD 4MB L2). Wave = 8 node-groups x 8 lanes; each group owns one
// node, its 8 lanes cover the 64-col slice with one b128 load per edge.
// Private per-lane accumulation of 8 cols; no cross-lane reduce. agg row-major.
__global__ __launch_bounds__(256) void spmm_tiled(
    const unsigned short* __restrict__ Mt, const int* __restrict__ row_ptr,
    const int* __restrict__ csr_src, unsigned short* __restrict__ agg) {
  const int tile = blockIdx.y;
  const int wv = threadIdx.x >> 6;
  const int l = threadIdx.x & 63;
  const int g = l >> 3;    // node group
  const int cs = l & 7;    // 16B slot within 128B slice
  const int node = blockIdx.x * 32 + wv * 8 + g;
  const unsigned short* base = Mt + (size_t)tile * N_NODES * 64 + cs * 8;

  int j = row_ptr[node];
  const int j1 = row_ptr[node + 1];
  float acc[8] = {};
  for (; j + 4 <= j1; j += 4) {
    int s0 = csr_src[j], s1 = csr_src[j + 1];
    int s2 = csr_src[j + 2], s3 = csr_src[j + 3];
    bf16x8 v0 = *(const bf16x8*)(base + (size_t)s0 * 64);
    bf16x8 v1 = *(const bf16x8*)(base + (size_t)s1 * 64);
    bf16x8 v2 = *(const bf16x8*)(base + (size_t)s2 * 64);
    bf16x8 v3 = *(const bf16x8*)(base + (size_t)s3 * 64);
#pragma unroll
    for (int i = 0; i < 8; ++i)
      acc[i] += (bf2f(v0[i]) + bf2f(v1[i])) + (bf2f(v2[i]) + bf2f(v3[i]));
  }
  for (; j < j1; ++j) {
    bf16x8 v = *(const bf16x8*)(base + (size_t)csr_src[j] * 64);
#pragma unroll
    for (int i = 0; i < 8; ++i) acc[i] += bf2f(v[i]);
  }
  bf16x8 o;
#pragma unroll
  for (int i = 0; i < 8; ++i) o[i] = f2bf(acc[i]);
  *(bf16x8*)(agg + (size_t)node * DP + tile * 64 + cs * 8) = o;
}

// ================= readout: softmax + per-graph sum (LDS-binned) ============
__global__ __launch_bounds__(256) void readout_kernel(
    const unsigned short* __restrict__ h, const float* __restrict__ Wro,
    const float* __restrict__ bro, const int* __restrict__ gid,
    float* __restrict__ out) {
  __shared__ float wro[2 * DP];
  __shared__ float bins[2 * N_GRAPHS];
  const int t = threadIdx.x;
  if (t < 2 * N_GRAPHS) bins[t] = 0.f;
  for (int i = t; i < 2 * DP; i += 256) wro[i] = (i < 2 * GD) ? Wro[i] : 0.f;
  __syncthreads();

  const int w = t >> 6, l = t & 63;
  const float b0 = bro[0], b1 = bro[1];
  const int nodeBase = blockIdx.x * 64 + w * 16;
  for (int it = 0; it < 16; ++it) {
    int node = nodeBase + it;
    float d0 = 0.f, d1 = 0.f;
    if (l < 40) {
      bf16x8 v = *(const bf16x8*)(h + (size_t)node * DP + l * 8);
#pragma unroll
      for (int j = 0; j < 8; ++j) {
        float f = bf2f((unsigned short)v[j]);
        int k = l * 8 + j;
        d0 += f * wro[2 * k];
        d1 += f * wro[2 * k + 1];
      }
    }
#pragma unroll
    for (int off = 32; off; off >>= 1) {
      d0 += __shfl_down(d0, off);
      d1 += __shfl_down(d1, off);
    }
    if (l == 0) {
      d0 += b0; d1 += b1;
      float m = fmaxf(d0, d1);
      float e0 = expf(d0 - m), e1 = expf(d1 - m);
      float inv = 1.f / (e0 + e1);
      int g = gid[node];
      atomicAdd(&bins[2 * g], e0 * inv);
      atomicAdd(&bins[2 * g + 1], e1 * inv);
    }
  }
  __syncthreads();
  if (t < 2 * N_GRAPHS) {
    float v = bins[t];
    if (v != 0.f) atomicAdd(&out[t], v);
  }
}

// ================= conversions =================
__global__ void conv_feats(const float* __restrict__ nf, unsigned short* __restrict__ X) {
  int idx = blockIdx.x * 256 + threadIdx.x;  // over N_NODES * 40 groups of 8
  int r = idx / 40, j = idx - r * 40;
  int c0 = j * 8;
  const float* rp = nf + (size_t)r * GD + c0;
  bf16x8 o;
  if (c0 + 8 <= GD) {
    float4 a = *(const float4*)rp;
    float4 b = *(const float4*)(rp + 4);
    o[0] = f2bf(a.x); o[1] = f2bf(a.y); o[2] = f2bf(a.z); o[3] = f2bf(a.w);
    o[4] = f2bf(b.x); o[5] = f2bf(b.y); o[6] = f2bf(b.z); o[7] = f2bf(b.w);
  } else {
#pragma unroll
    for (int i = 0; i < 8; ++i) {
      int c = c0 + i;
      o[i] = f2bf(c < GD ? rp[i] : 0.f);
    }
  }
  *(bf16x8*)(X + (size_t)idx * 8) = o;
}

struct WPtrs {
  const float* W[7];
  const float* b[7];
};

__global__ void conv_weights(WPtrs p, unsigned short* __restrict__ Wt,
                             float* __restrict__ biasP) {
  int wi = blockIdx.y;
  int idx = blockIdx.x * 256 + threadIdx.x;  // < DP*DP
  int n = idx / DP, k = idx - n * DP;
  float v = (n < GD && k < GD) ? p.W[wi][(size_t)k * GD + n] : 0.f;
  Wt[(size_t)wi * DP * DP + idx] = f2bf(v);
  if (idx < DP) biasP[wi * DP + idx] = (idx < GD) ? p.b[wi][idx] : 0.f;
}

// ================= host =================
extern "C" void kernel_launch(void* const* d_in, const int* in_sizes, int n_in,
                              void* d_out, int out_size, void* d_ws, size_t ws_size,
                              hipStream_t stream) {
  const float* node_feats = (const float*)d_in[0];
  const int* src = (const int*)d_in[17];
  const int* dst = (const int*)d_in[18];
  const int* gid = (const int*)d_in[19];
  float* out = (float*)d_out;

  WPtrs wp;
  wp.W[0] = (const float*)d_in[1];   wp.b[0] = (const float*)d_in[2];   // lift
  wp.W[1] = (const float*)d_in[3];   wp.b[1] = (const float*)d_in[4];   // Wf1
  wp.W[2] = (const float*)d_in[5];   wp.b[2] = (const float*)d_in[6];   // Wo1
  wp.W[3] = (const float*)d_in[7];   wp.b[3] = (const float*)d_in[8];   // Wf2
  wp.W[4] = (const float*)d_in[9];   wp.b[4] = (const float*)d_in[10];  // Wo2
  wp.W[5] = (const float*)d_in[11];  wp.b[5] = (const float*)d_in[12];  // Wf3
  wp.W[6] = (const float*)d_in[13];  wp.b[6] = (const float*)d_in[14];  // Wo3
  const float* W_ro = (const float*)d_in[15];
  const float* b_ro = (const float*)d_in[16];

  char* p = (char*)d_ws;
  unsigned short* X = (unsigned short*)p;  p += (size_t)N_NODES * DP * 2;
  unsigned short* Y = (unsigned short*)p;  p += (size_t)N_NODES * DP * 2;
  unsigned short* Wt = (unsigned short*)p; p += (size_t)7 * DP * DP * 2;
  float* biasP = (float*)p;                p += 7 * DP * 4;
  int* cnt = (int*)p;                      p += N_NODES * 4;
  int* row_ptr = (int*)p;                  p += (N_NODES + 16) * 4;
  int* row_fill = (int*)p;                 p += N_NODES * 4;
  int* csr_src = (int*)p;                  p += N_EDGES * 4;

  // --- CSR build ---
  hipMemsetAsync(cnt, 0, N_NODES * sizeof(int), stream);
  hist_kernel<<<N_EDGES / 256, 256, 0, stream>>>(dst, cnt);
  scan_kernel<<<1, 256, 0, stream>>>(cnt, row_ptr, row_fill);
  scatter_kernel<<<N_EDGES / 256, 256, 0, stream>>>(src, dst, row_fill, csr_src);

  // --- conversions ---
  conv_feats<<<(N_NODES * 40) / 256, 256, 0, stream>>>(node_feats, X);
  conv_weights<<<dim3(DP * DP / 256, 7), 256, 0, stream>>>(wp, Wt, biasP);

  const size_t WSZ = (size_t)DP * DP;
  dim3 ggrid(DP / BN, N_NODES / BM);       // (2, 256) = 512 blocks
  dim3 sgrid(N_NODES / 32, NTILE);         // (512 node-blocks, 5 col phases)

  // lift: Y = X @ W0 + b0 (no relu). h = Y.
  gemm_mfma<false, false><<<ggrid, 256, 0, stream>>>(X, Wt + 0 * WSZ, biasP, Y);

  // L1: msg(tiled) X <- Y; agg Y <- X; h X <- Y
  gemm_mfma<true, true><<<ggrid, 256, 0, stream>>>(Y, Wt + 1 * WSZ, biasP + 1 * DP, X);
  spmm_tiled<<<sgrid, 256, 0, stream>>>(X, row_ptr, csr_src, Y);
  gemm_mfma<true, false><<<ggrid, 256, 0, stream>>>(Y, Wt + 2 * WSZ, biasP + 2 * DP, X);
  // L2: h ends in Y
  gemm_mfma<true, true><<<ggrid, 256, 0, stream>>>(X, Wt + 3 * WSZ, biasP + 3 * DP, Y);
  spmm_tiled<<<sgrid, 256, 0, stream>>>(Y, row_ptr, csr_src, X);
  gemm_mfma<true, false><<<ggrid, 256, 0, stream>>>(X, Wt + 4 * WSZ, biasP + 4 * DP, Y);
  // L3: h ends in X
  gemm_mfma<true, true><<<ggrid, 256, 0, stream>>>(Y, Wt + 5 * WSZ, biasP + 5 * DP, X);
  spmm_tiled<<<sgrid, 256, 0, stream>>>(X, row_ptr, csr_src, Y);
  gemm_mfma<true, false><<<ggrid, 256, 0, stream>>>(Y, Wt + 6 * WSZ, biasP + 6 * DP, X);

  // --- readout ---
  hipMemsetAsync(out, 0, (size_t)out_size * sizeof(float), stream);
  readout_kernel<<<N_NODES / 64, 256, 0, stream>>>(X, W_ro, b_ro, gid, out);
}

// Round 5
// 209.961 us; speedup vs baseline: 5.7996x; 1.0072x over previous
//
#include <hip/hip_runtime.h>
#include <hip/hip_bf16.h>

#define N_NODES 16384
#define N_EDGES 262144
#define GD 300        // real feature dim
#define DP 320        // padded feature dim (pads are exact zeros)
#define N_GRAPHS 64
#define NTILE 5       // 5 column tiles of 64

typedef short bf16x8 __attribute__((ext_vector_type(8)));
typedef float f32x4 __attribute__((ext_vector_type(4)));

__device__ static inline unsigned short f2bf(float v) {
  __hip_bfloat16 b = __float2bfloat16(v);
  return __builtin_bit_cast(unsigned short, b);
}
__device__ static inline float bf2f(unsigned short u) {
  return __bfloat162float(__builtin_bit_cast(__hip_bfloat16, u));
}

#define GLOAD_LDS16(g, l)                                                    \
  __builtin_amdgcn_global_load_lds(                                          \
      (const __attribute__((address_space(1))) void*)(g),                    \
      (__attribute__((address_space(3))) void*)(l), 16, 0, 0)

// ================= bf16 MFMA GEMM =================
// C[M,DP] = act(A[M,DP](bf16) @ W + bias), Wt[n][k] pre-transposed bf16.
// BM=64 rows, BN=320 (full width), BK=64. 512 threads = 8 waves (2 row x 4
// col); per-wave 32x80 = 2x5 frags of 16x16x32. LDS rows 128 B; 16B-slot s
// stores global slot s^(row&7) -> conflict-free ds_read_b128; staged via
// global_load_lds with pre-swizzled global source. A is read exactly once.
// TILED: C written column-tile-major Mt[tile][row][64] for the SpMM gather.
// RO:   no C write; fused h3@W_ro -> softmax -> per-graph bins -> atomics.
constexpr int BM = 64, BN = 320, BK = 64, NKT = DP / BK;  // 5 K-tiles
constexpr int A_BYTES = BM * 128;            // 8192
constexpr int B_BYTES = BN * 128;            // 40960
constexpr int BUF_BYTES = A_BYTES + B_BYTES; // 49152

template <bool RELU, bool TILED, bool RO>
__global__ __launch_bounds__(512) void gemm_mfma(
    const unsigned short* __restrict__ A, const unsigned short* __restrict__ Wt,
    const float* __restrict__ biasP, unsigned short* __restrict__ C,
    const float* __restrict__ Wro, const float* __restrict__ bro,
    const int* __restrict__ gid, float* __restrict__ out) {
  __shared__ __align__(16) char smem[2 * BUF_BYTES];  // 98304 B -> 1 block/CU
  __shared__ float wroL[2 * DP];
  __shared__ float rowacc[2 * BM];
  __shared__ float binsL[2 * N_GRAPHS];

  const int bm = blockIdx.y * BM;
  const int bn = blockIdx.x * BN;  // 0 when BN==DP
  const int t = threadIdx.x;
  const int w = t >> 6;   // wave 0..7
  const int l = t & 63;
  const int wr = w & 1;   // wave row -> rows wr*32..+31
  const int wc = w >> 1;  // wave col 0..3 -> cols wc*80..+79

  const int lr = l >> 3;              // row within 8-row group
  const int sg = (l & 7) ^ lr;        // pre-swizzled global 16B-slot

  if (RO) {
    for (int i = t; i < DP; i += 512) {
      wroL[2 * i]     = (i < GD) ? Wro[2 * i] : 0.f;
      wroL[2 * i + 1] = (i < GD) ? Wro[2 * i + 1] : 0.f;
    }
    if (t < 2 * BM) rowacc[t] = 0.f;
    if (t < 2 * N_GRAPHS) binsL[t] = 0.f;
  }

  f32x4 acc[2][5] = {};

  auto stage = [&](int tk, int buf) {
    const int k0 = tk * BK;
    char* lb = smem + buf * BUF_BYTES;
#pragma unroll
    for (int i = 0; i < 6; ++i) {
      int g = w + 8 * i;  // 48 groups: 8 for A, 40 for Bt
      if (g < 8) {
        const unsigned short* gp =
            A + (size_t)(bm + g * 8 + lr) * DP + k0 + 8 * sg;
        GLOAD_LDS16(gp, lb + g * 1024);
      } else {
        int gb = g - 8;
        const unsigned short* gp =
            Wt + (size_t)(bn + gb * 8 + lr) * DP + k0 + 8 * sg;
        GLOAD_LDS16(gp, lb + A_BYTES + gb * 1024);
      }
    }
  };

  auto compute = [&](int buf) {
    const char* lA = smem + buf * BUF_BYTES;
    const char* lB = lA + A_BYTES;
#pragma unroll
    for (int ks = 0; ks < 2; ++ks) {
      bf16x8 a[2], b[5];
#pragma unroll
      for (int m = 0; m < 2; ++m) {
        int r = wr * 32 + m * 16 + (l & 15);
        int slot = (ks * 4 + (l >> 4)) ^ (r & 7);
        a[m] = *(const bf16x8*)(lA + r * 128 + slot * 16);
      }
#pragma unroll
      for (int n = 0; n < 5; ++n) {
        int r = wc * 80 + n * 16 + (l & 15);
        int slot = (ks * 4 + (l >> 4)) ^ (r & 7);
        b[n] = *(const bf16x8*)(lB + r * 128 + slot * 16);
      }
#pragma unroll
      for (int m = 0; m < 2; ++m)
#pragma unroll
        for (int n = 0; n < 5; ++n)
          acc[m][n] =
              __builtin_amdgcn_mfma_f32_16x16x32_bf16(a[m], b[n], acc[m][n], 0, 0, 0);
    }
  };

  stage(0, 0);
  for (int tk = 0; tk < NKT; ++tk) {
    asm volatile("s_waitcnt vmcnt(0)" ::: "memory");
    __syncthreads();
    if (tk + 1 < NKT) stage(tk + 1, (tk + 1) & 1);
    compute(tk & 1);
  }

  if (!RO) {
#pragma unroll
    for (int m = 0; m < 2; ++m) {
#pragma unroll
      for (int n = 0; n < 5; ++n) {
        int col = bn + wc * 80 + n * 16 + (l & 15);
        float bv = biasP[col];
#pragma unroll
        for (int r = 0; r < 4; ++r) {
          int row = bm + wr * 32 + m * 16 + (l >> 4) * 4 + r;
          float v = acc[m][n][r] + bv;
          if (RELU) v = fmaxf(v, 0.f);
          size_t idx;
          if (TILED)  // 16-wide frag lies in one 64-col tile
            idx = ((size_t)(col >> 6) * N_NODES + row) * 64 + (col & 63);
          else
            idx = (size_t)row * DP + col;
          C[idx] = f2bf(v);
        }
      }
    }
  } else {
    // fused readout: d = relu(acc+bias) . Wro, reduce per row, softmax, bin
    float bv[5];
#pragma unroll
    for (int n = 0; n < 5; ++n) bv[n] = biasP[wc * 80 + n * 16 + (l & 15)];
#pragma unroll
    for (int m = 0; m < 2; ++m) {
#pragma unroll
      for (int r = 0; r < 4; ++r) {
        float s0 = 0.f, s1 = 0.f;
#pragma unroll
        for (int n = 0; n < 5; ++n) {
          int col = wc * 80 + n * 16 + (l & 15);
          float v = fmaxf(acc[m][n][r] + bv[n], 0.f);
          s0 += v * wroL[2 * col];
          s1 += v * wroL[2 * col + 1];
        }
#pragma unroll
        for (int off = 1; off < 16; off <<= 1) {
          s0 += __shfl_xor(s0, off);
          s1 += __shfl_xor(s1, off);
        }
        if ((l & 15) == 0) {
          int row = wr * 32 + m * 16 + (l >> 4) * 4 + r;
          atomicAdd(&rowacc[2 * row], s0);
          atomicAdd(&rowacc[2 * row + 1], s1);
        }
      }
    }
    __syncthreads();
    if (t < BM) {
      float d0 = rowacc[2 * t] + bro[0];
      float d1 = rowacc[2 * t + 1] + bro[1];
      float mx = fmaxf(d0, d1);
      float e0 = expf(d0 - mx), e1 = expf(d1 - mx);
      float inv = 1.f / (e0 + e1);
      int g = gid[bm + t];
      atomicAdd(&binsL[2 * g], e0 * inv);
      atomicAdd(&binsL[2 * g + 1], e1 * inv);
    }
    __syncthreads();
    if (t < 2 * N_GRAPHS) {
      float v = binsL[t];
      if (v != 0.f) atomicAdd(&out[t], v);
    }
  }
}

// ================= CSR build =================
__global__ void hist_kernel(const int* __restrict__ dst, int* __restrict__ cnt) {
  int e = blockIdx.x * blockDim.x + threadIdx.x;
  if (e < N_EDGES) atomicAdd(&cnt[dst[e]], 1);
}

__global__ __launch_bounds__(256) void scan_kernel(
    const int* __restrict__ cnt, int* __restrict__ row_ptr, int* __restrict__ row_fill) {
  __shared__ int sums[256];
  const int t = threadIdx.x;
  const int base = t * 64;
  int s = 0;
  for (int i = 0; i < 64; ++i) s += cnt[base + i];
  sums[t] = s;
  __syncthreads();
  for (int off = 1; off < 256; off <<= 1) {
    int x = (t >= off) ? sums[t - off] : 0;
    __syncthreads();
    sums[t] += x;
    __syncthreads();
  }
  int run = sums[t] - s;
  for (int i = 0; i < 64; ++i) {
    int c = cnt[base + i];
    row_ptr[base + i] = run;
    row_fill[base + i] = run;
    run += c;
  }
  if (t == 255) row_ptr[N_NODES] = run;
}

__global__ void scatter_kernel(const int* __restrict__ src, const int* __restrict__ dst,
                               int* __restrict__ row_fill, int* __restrict__ csr_src) {
  int e = blockIdx.x * blockDim.x + threadIdx.x;
  if (e >= N_EDGES) return;
  int pos = atomicAdd(&row_fill[dst[e]], 1);
  csr_src[pos] = src[e];
}

// ========== SpMM aggregate: tiled gather, L2-resident per column phase ======
__global__ __launch_bounds__(256) void spmm_tiled(
    const unsigned short* __restrict__ Mt, const int* __restrict__ row_ptr,
    const int* __restrict__ csr_src, unsigned short* __restrict__ agg) {
  const int tile = blockIdx.y;
  const int wv = threadIdx.x >> 6;
  const int l = threadIdx.x & 63;
  const int g = l >> 3;    // node group
  const int cs = l & 7;    // 16B slot within 128B slice
  const int node = blockIdx.x * 32 + wv * 8 + g;
  const unsigned short* base = Mt + (size_t)tile * N_NODES * 64 + cs * 8;

  int j = row_ptr[node];
  const int j1 = row_ptr[node + 1];
  float acc[8] = {};
  for (; j + 4 <= j1; j += 4) {
    int s0 = csr_src[j], s1 = csr_src[j + 1];
    int s2 = csr_src[j + 2], s3 = csr_src[j + 3];
    bf16x8 v0 = *(const bf16x8*)(base + (size_t)s0 * 64);
    bf16x8 v1 = *(const bf16x8*)(base + (size_t)s1 * 64);
    bf16x8 v2 = *(const bf16x8*)(base + (size_t)s2 * 64);
    bf16x8 v3 = *(const bf16x8*)(base + (size_t)s3 * 64);
#pragma unroll
    for (int i = 0; i < 8; ++i)
      acc[i] += (bf2f(v0[i]) + bf2f(v1[i])) + (bf2f(v2[i]) + bf2f(v3[i]));
  }
  for (; j < j1; ++j) {
    bf16x8 v = *(const bf16x8*)(base + (size_t)csr_src[j] * 64);
#pragma unroll
    for (int i = 0; i < 8; ++i) acc[i] += bf2f(v[i]);
  }
  bf16x8 o;
#pragma unroll
  for (int i = 0; i < 8; ++i) o[i] = f2bf(acc[i]);
  *(bf16x8*)(agg + (size_t)node * DP + tile * 64 + cs * 8) = o;
}

// ================= conversions =================
__global__ void conv_feats(const float* __restrict__ nf, unsigned short* __restrict__ X) {
  int idx = blockIdx.x * 256 + threadIdx.x;  // over N_NODES * 40 groups of 8
  int r = idx / 40, j = idx - r * 40;
  int c0 = j * 8;
  const float* rp = nf + (size_t)r * GD + c0;
  bf16x8 o;
  if (c0 + 8 <= GD) {
    float4 a = *(const float4*)rp;
    float4 b = *(const float4*)(rp + 4);
    o[0] = f2bf(a.x); o[1] = f2bf(a.y); o[2] = f2bf(a.z); o[3] = f2bf(a.w);
    o[4] = f2bf(b.x); o[5] = f2bf(b.y); o[6] = f2bf(b.z); o[7] = f2bf(b.w);
  } else {
#pragma unroll
    for (int i = 0; i < 8; ++i) {
      int c = c0 + i;
      o[i] = f2bf(c < GD ? rp[i] : 0.f);
    }
  }
  *(bf16x8*)(X + (size_t)idx * 8) = o;
}

struct WPtrs {
  const float* W[7];   // [0..5] transposed sources, [6] = Wlift original
  const float* b[5];   // biases for slots 3..7
};

// Wt slots: 0=Wc_t(out), 1=Wf1t(tmp), 2=Wlift_orig(tmp), 3=Wo1t, 4=Wf2t,
// 5=Wo2t, 6=Wf3t, 7=Wo3t.  bias slots: 0=bc, 1=zeros, 3..7 as Wt.
__global__ void conv_weights(WPtrs p, unsigned short* __restrict__ Wt,
                             float* __restrict__ biasP) {
  int wi = blockIdx.y;  // 0..6
  int idx = blockIdx.x * 256 + threadIdx.x;  // < DP*DP
  int slot, r = idx / DP, c = idx - r * DP;
  float v;
  if (wi < 6) {  // transposed: dest[n][k] = W[k][n]
    slot = (wi == 0) ? 1 : 2 + wi;
    v = (r < GD && c < GD) ? p.W[wi][(size_t)c * GD + r] : 0.f;
  } else {       // original: dest[r][c] = W[r][c]
    slot = 2;
    v = (r < GD && c < GD) ? p.W[6][(size_t)r * GD + c] : 0.f;
  }
  Wt[(size_t)slot * DP * DP + idx] = f2bf(v);
  if (idx < DP && wi >= 1 && wi < 6)
    biasP[(2 + wi) * DP + idx] = (idx < GD) ? p.b[wi - 1][idx] : 0.f;
}

// bc[n] = sum_j bl[j]*Wf1[j][n] + bf1[n]; also zero-bias slot
__global__ __launch_bounds__(320) void bias_fuse(
    const float* __restrict__ bl, const float* __restrict__ Wf1,
    const float* __restrict__ bf1, float* __restrict__ biasP) {
  int n = threadIdx.x;  // 0..319
  float s = 0.f;
  if (n < GD) {
    s = bf1[n];
    for (int j = 0; j < GD; ++j) s += bl[j] * Wf1[(size_t)j * GD + n];
  }
  biasP[n] = s;            // slot 0 = bc
  biasP[DP + n] = 0.f;     // slot 1 = zeros
}

// ================= host =================
extern "C" void kernel_launch(void* const* d_in, const int* in_sizes, int n_in,
                              void* d_out, int out_size, void* d_ws, size_t ws_size,
                              hipStream_t stream) {
  const float* node_feats = (const float*)d_in[0];
  const float* W_lift = (const float*)d_in[1];
  const float* b_lift = (const float*)d_in[2];
  const float* Wf1 = (const float*)d_in[3];
  const float* bf1 = (const float*)d_in[4];
  const float* W_ro = (const float*)d_in[15];
  const float* b_ro = (const float*)d_in[16];
  const int* src = (const int*)d_in[17];
  const int* dst = (const int*)d_in[18];
  const int* gid = (const int*)d_in[19];
  float* out = (float*)d_out;

  WPtrs wp;
  wp.W[0] = Wf1;                     // -> slot 1 (tmp, transposed)
  wp.W[1] = (const float*)d_in[5];   wp.b[0] = (const float*)d_in[6];   // Wo1 -> 3
  wp.W[2] = (const float*)d_in[7];   wp.b[1] = (const float*)d_in[8];   // Wf2 -> 4
  wp.W[3] = (const float*)d_in[9];   wp.b[2] = (const float*)d_in[10];  // Wo2 -> 5
  wp.W[4] = (const float*)d_in[11];  wp.b[3] = (const float*)d_in[12];  // Wf3 -> 6
  wp.W[5] = (const float*)d_in[13];  wp.b[4] = (const float*)d_in[14];  // Wo3 -> 7
  wp.W[6] = W_lift;                  // -> slot 2 (tmp, original orient)

  char* p = (char*)d_ws;
  unsigned short* X = (unsigned short*)p;  p += (size_t)N_NODES * DP * 2;
  unsigned short* Y = (unsigned short*)p;  p += (size_t)N_NODES * DP * 2;
  unsigned short* Wt = (unsigned short*)p; p += (size_t)8 * DP * DP * 2;
  float* biasP = (float*)p;                p += 8 * DP * 4;
  int* cnt = (int*)p;                      p += N_NODES * 4;
  int* row_ptr = (int*)p;                  p += (N_NODES + 16) * 4;
  int* row_fill = (int*)p;                 p += N_NODES * 4;
  int* csr_src = (int*)p;                  p += N_EDGES * 4;

  const size_t WSZ = (size_t)DP * DP;

  // --- CSR build ---
  hipMemsetAsync(cnt, 0, N_NODES * sizeof(int), stream);
  hist_kernel<<<N_EDGES / 256, 256, 0, stream>>>(dst, cnt);
  scan_kernel<<<1, 256, 0, stream>>>(cnt, row_ptr, row_fill);
  scatter_kernel<<<N_EDGES / 256, 256, 0, stream>>>(src, dst, row_fill, csr_src);

  // --- conversions + lift-fold precompute ---
  conv_feats<<<(N_NODES * 40) / 256, 256, 0, stream>>>(node_feats, X);
  conv_weights<<<dim3(DP * DP / 256, 7), 256, 0, stream>>>(wp, Wt, biasP);
  bias_fuse<<<1, 320, 0, stream>>>(b_lift, Wf1, bf1, biasP);
  // Wc_t = Wf1t @ Wlift_orig (M=320)
  gemm_mfma<false, false, false><<<dim3(1, DP / BM), 512, 0, stream>>>(
      Wt + 1 * WSZ, Wt + 2 * WSZ, biasP + 1 * DP, Wt + 0 * WSZ,
      nullptr, nullptr, nullptr, nullptr);

  hipMemsetAsync(out, 0, (size_t)out_size * sizeof(float), stream);

  dim3 ggrid(1, N_NODES / BM);             // 256 blocks
  dim3 sgrid(N_NODES / 32, NTILE);         // (512, 5)

  // L1: msg1 = relu(X @ Wc + bc) [tiled] ; agg ; h1 = relu(agg@Wo1+bo1)
  gemm_mfma<true, true, false><<<ggrid, 512, 0, stream>>>(
      X, Wt + 0 * WSZ, biasP + 0 * DP, Y, nullptr, nullptr, nullptr, nullptr);
  spmm_tiled<<<sgrid, 256, 0, stream>>>(Y, row_ptr, csr_src, X);
  gemm_mfma<true, false, false><<<ggrid, 512, 0, stream>>>(
      X, Wt + 3 * WSZ, biasP + 3 * DP, Y, nullptr, nullptr, nullptr, nullptr);
  // L2
  gemm_mfma<true, true, false><<<ggrid, 512, 0, stream>>>(
      Y, Wt + 4 * WSZ, biasP + 4 * DP, X, nullptr, nullptr, nullptr, nullptr);
  spmm_tiled<<<sgrid, 256, 0, stream>>>(X, row_ptr, csr_src, Y);
  gemm_mfma<true, false, false><<<ggrid, 512, 0, stream>>>(
      Y, Wt + 5 * WSZ, biasP + 5 * DP, X, nullptr, nullptr, nullptr, nullptr);
  // L3
  gemm_mfma<true, true, false><<<ggrid, 512, 0, stream>>>(
      X, Wt + 6 * WSZ, biasP + 6 * DP, Y, nullptr, nullptr, nullptr, nullptr);
  spmm_tiled<<<sgrid, 256, 0, stream>>>(Y, row_ptr, csr_src, X);
  // final Wo3 GEMM with fused readout (no C write)
  gemm_mfma<true, false, true><<<ggrid, 512, 0, stream>>>(
      X, Wt + 7 * WSZ, biasP + 7 * DP, nullptr, W_ro, b_ro, gid, out);
}